// Round 2
// baseline (781.119 us; speedup 1.0000x reference)
//
#include <hip/hip_runtime.h>
#include <hip/hip_bf16.h>

typedef __attribute__((ext_vector_type(8))) short short8;
typedef __attribute__((ext_vector_type(4))) float f32x4;

static constexpr int Tt   = 4096;
static constexpr int Cc   = 2048;
static constexpr int NH   = 16;
static constexpr int HD   = 128;
static constexpr int QKVO = 3072;   // (16 + 2*4) * 128
static constexpr int W1   = 1023;   // WINDOW - 1

#define GLDS16(gp, lp)                                                        \
  __builtin_amdgcn_global_load_lds(                                           \
      (const __attribute__((address_space(1))) unsigned int*)(gp),            \
      (__attribute__((address_space(3))) unsigned int*)(lp), 16, 0, 0)

// ---------------- fp32 -> bf16 convert (vectorized) ----------------
__global__ void cvt4(const float* __restrict__ in,
                     __hip_bfloat16* __restrict__ out, int n) {
  int i = (blockIdx.x * blockDim.x + threadIdx.x) * 4;
  if (i >= n) return;
  float4 v = *(const float4*)&in[i];
  union { ushort4 u; __hip_bfloat16 b[4]; } o;
  o.b[0] = __float2bfloat16(v.x);
  o.b[1] = __float2bfloat16(v.y);
  o.b[2] = __float2bfloat16(v.z);
  o.b[3] = __float2bfloat16(v.w);
  *(ushort4*)&out[i] = o.u;
}

// ------------- transpose + convert: W[K][N] -> Wt[N][K] bf16 -------------
__global__ void tconv(const float* __restrict__ W,
                      __hip_bfloat16* __restrict__ Wt, int K, int N) {
  __shared__ float tile[32][33];
  const int k0 = blockIdx.x * 32, n0 = blockIdx.y * 32;
  const int tx = threadIdx.x, ty = threadIdx.y;  // 32 x 8
#pragma unroll
  for (int r = 0; r < 4; ++r)
    tile[ty * 4 + r][tx] = W[(size_t)(k0 + ty * 4 + r) * N + n0 + tx];
  __syncthreads();
#pragma unroll
  for (int r = 0; r < 4; ++r)
    Wt[(size_t)(n0 + ty * 4 + r) * K + k0 + tx] =
        __float2bfloat16(tile[tx][ty * 4 + r]);
}

// ---------------- bf16 GEMM: C[M][N] = A[M][K] * Bt[N][K]^T ----------------
// m97 structure: 128x128 tile, 4 waves (2x2), 4x4 16x16x32 acc per wave,
// global_load_lds width-16 staging, BK=32.
template <bool OUT_BF16>
__global__ __launch_bounds__(256) void gemm_bt(
    const __hip_bfloat16* __restrict__ A, const __hip_bfloat16* __restrict__ Bt,
    void* __restrict__ Cout, int M, int N, int K) {
  __shared__ __hip_bfloat16 As[128 * 32];
  __shared__ __hip_bfloat16 Bs[128 * 32];
  const int tid = threadIdx.x;
  const int lane = tid & 63, wid = tid >> 6;
  const int l15 = lane & 15, lhi = lane >> 4;
  const int m0 = blockIdx.y * 128, n0 = blockIdx.x * 128;
  const int wm = wid >> 1, wn = wid & 1;
  f32x4 acc[4][4] = {};
  for (int k0 = 0; k0 < K; k0 += 32) {
#pragma unroll
    for (int cc = 0; cc < 2; ++cc) {
      const int ebase = cc * 2048 + wid * 512;  // wave-uniform elem base
      const int el = ebase + lane * 8;          // this lane's 8 elems
      const int row = el >> 5, col = el & 31;
      GLDS16(A + (size_t)(m0 + row) * K + k0 + col, As + ebase);
      GLDS16(Bt + (size_t)(n0 + row) * K + k0 + col, Bs + ebase);
    }
    __syncthreads();
    short8 af[4], bfr[4];
#pragma unroll
    for (int i = 0; i < 4; ++i)
      af[i] = *(const short8*)&As[(wm * 64 + i * 16 + l15) * 32 + lhi * 8];
#pragma unroll
    for (int j = 0; j < 4; ++j)
      bfr[j] = *(const short8*)&Bs[(wn * 64 + j * 16 + l15) * 32 + lhi * 8];
#pragma unroll
    for (int i = 0; i < 4; ++i)
#pragma unroll
      for (int j = 0; j < 4; ++j)
        acc[i][j] = __builtin_amdgcn_mfma_f32_16x16x32_bf16(af[i], bfr[j],
                                                            acc[i][j], 0, 0, 0);
    __syncthreads();
  }
#pragma unroll
  for (int i = 0; i < 4; ++i)
#pragma unroll
    for (int r = 0; r < 4; ++r) {
      const int row = m0 + wm * 64 + i * 16 + lhi * 4 + r;
#pragma unroll
      for (int j = 0; j < 4; ++j) {
        const int col = n0 + wn * 64 + j * 16 + l15;
        if (OUT_BF16)
          ((__hip_bfloat16*)Cout)[(size_t)row * N + col] =
              __float2bfloat16(acc[i][j][r]);
        else
          ((float*)Cout)[(size_t)row * N + col] = acc[i][j][r];
      }
    }
}

// ------- RoPE + scramble-scatter: qkv[t][c] -> qb[t'][h*128+d], kb, vb -------
// Reference's reshape scramble: q: u=(kv<<14)|(slot<<12)|t, (t',h)=(u>>4,u&15)
//                               k/v: u2=(kv<<12)|t, (t'',hk)=(u2>>2,u2&3)
__global__ void rope_scatter(const __hip_bfloat16* __restrict__ qkv,
                             const float* __restrict__ fc,
                             __hip_bfloat16* __restrict__ qb,
                             __hip_bfloat16* __restrict__ kb,
                             __hip_bfloat16* __restrict__ vb) {
  const int p = blockIdx.x * blockDim.x + threadIdx.x;  // 0..1535
  const int t = blockIdx.y;
  const int c = p * 2;
  const int kv = c / 768;
  const int rem = c - kv * 768;
  const int slot = rem >> 7;
  const int d = rem & 127;
  const ushort2 xy = *(const ushort2*)&qkv[(size_t)t * QKVO + c];
  const float x0 = __bfloat162float(*(const __hip_bfloat16*)&xy.x);
  const float x1 = __bfloat162float(*(const __hip_bfloat16*)&xy.y);
  union { ushort2 uu; __hip_bfloat16 b[2]; } o;
  if (slot < 4) {
    const unsigned u = ((unsigned)kv << 14) | ((unsigned)slot << 12) | (unsigned)t;
    const int tp = u >> 4, h = u & 15;
    const float2 cs = *(const float2*)&fc[(size_t)tp * 128 + (d >> 1) * 2];
    o.b[0] = __float2bfloat16(x0 * cs.x - x1 * cs.y);
    o.b[1] = __float2bfloat16(x1 * cs.x + x0 * cs.y);
    *(ushort2*)&qb[(size_t)tp * Cc + h * HD + d] = o.uu;
  } else {
    const unsigned u2 = ((unsigned)kv << 12) | (unsigned)t;
    const int tp = u2 >> 2, hk = u2 & 3;
    if (slot == 4) {
      const float2 cs = *(const float2*)&fc[(size_t)tp * 128 + (d >> 1) * 2];
      o.b[0] = __float2bfloat16(x0 * cs.x - x1 * cs.y);
      o.b[1] = __float2bfloat16(x1 * cs.x + x0 * cs.y);
      *(ushort2*)&kb[(size_t)tp * 512 + hk * HD + d] = o.uu;
    } else {
      o.uu = xy;
      *(ushort2*)&vb[(size_t)tp * 512 + hk * HD + d] = o.uu;
    }
  }
}

// ------------- banded GQA flash attention (KVBLK=64, 4 waves) -------------
// Each block: 64 q-rows of one head; wave w owns rows [q0+16w, q0+16w+16).
// K-tile [64][128] and V^T-tile [128][64] staged in LDS; P round-trips
// through per-wave LDS to re-fragment for the PV MFMA.
__global__ __launch_bounds__(256) void attn_band(
    const __hip_bfloat16* __restrict__ qb, const __hip_bfloat16* __restrict__ kb,
    const __hip_bfloat16* __restrict__ vb, __hip_bfloat16* __restrict__ yb) {
  __shared__ __hip_bfloat16 kt[64 * 128];   // [j][d]
  __shared__ __hip_bfloat16 vt[128 * 64];   // [d][j] (transposed)
  __shared__ __hip_bfloat16 pl[4][16 * 64]; // per-wave P round-trip
  const int tid = threadIdx.x, lane = tid & 63, wid = tid >> 6;
  const int l15 = lane & 15, lhi = lane >> 4;
  const int q0 = blockIdx.x * 64, h = blockIdx.y;
  const int kvh = h >> 2;
  const int qrow = q0 + wid * 16 + l15;
  short8 aq[4];
#pragma unroll
  for (int kc = 0; kc < 4; ++kc)
    aq[kc] = *(const short8*)&qb[(size_t)qrow * Cc + h * HD + kc * 32 + lhi * 8];
  f32x4 o[8] = {};
  float mrow[4] = {-1e30f, -1e30f, -1e30f, -1e30f};
  float lrow[4] = {0.f, 0.f, 0.f, 0.f};
  const int js = (q0 - W1 > 0 ? q0 - W1 : 0) & ~63;
  const int jeu = q0 + 64 + W1;
  const int je = jeu < Tt ? jeu : Tt;
  const float scale = 0.08838834764831845f;  // 1/sqrt(128)
  for (int j0 = js; j0 < je; j0 += 64) {
    __syncthreads();
#pragma unroll
    for (int cc = 0; cc < 4; ++cc) {
      const int e = cc * 2048 + tid * 8;
      const int row = e >> 7, col = e & 127;
      int jc = j0 + row;
      jc = jc < Tt - 1 ? jc : Tt - 1;
      *(short8*)&kt[e] = *(const short8*)&kb[(size_t)jc * 512 + kvh * HD + col];
      short8 vv = *(const short8*)&vb[(size_t)jc * 512 + kvh * HD + col];
#pragma unroll
      for (int q = 0; q < 8; ++q)
        vt[(col + q) * 64 + row] = ((const __hip_bfloat16*)&vv)[q];
    }
    __syncthreads();
    f32x4 s[4] = {};
#pragma unroll
    for (int jt = 0; jt < 4; ++jt)
#pragma unroll
      for (int kc = 0; kc < 4; ++kc) {
        const short8 bk =
            *(const short8*)&kt[(jt * 16 + l15) * 128 + kc * 32 + lhi * 8];
        s[jt] = __builtin_amdgcn_mfma_f32_16x16x32_bf16(aq[kc], bk, s[jt], 0, 0, 0);
      }
    float val[4][4], pm[4];
#pragma unroll
    for (int jt = 0; jt < 4; ++jt)
#pragma unroll
      for (int r = 0; r < 4; ++r) {
        const int j = j0 + jt * 16 + l15;
        const int i = q0 + wid * 16 + lhi * 4 + r;
        const int diff = i > j ? i - j : j - i;
        const bool ok = (j < Tt) && (diff <= W1);
        val[jt][r] = ok ? s[jt][r] * scale : -1e30f;
      }
#pragma unroll
    for (int r = 0; r < 4; ++r) {
      float v = fmaxf(fmaxf(val[0][r], val[1][r]), fmaxf(val[2][r], val[3][r]));
      v = fmaxf(v, __shfl_xor(v, 1));
      v = fmaxf(v, __shfl_xor(v, 2));
      v = fmaxf(v, __shfl_xor(v, 4));
      v = fmaxf(v, __shfl_xor(v, 8));
      pm[r] = v;
    }
    float esc[4];
#pragma unroll
    for (int r = 0; r < 4; ++r) {
      const float mn = fmaxf(mrow[r], pm[r]);
      esc[r] = __expf(mrow[r] - mn);
      mrow[r] = mn;
    }
    float rs[4] = {0.f, 0.f, 0.f, 0.f};
#pragma unroll
    for (int jt = 0; jt < 4; ++jt)
#pragma unroll
      for (int r = 0; r < 4; ++r) {
        const float p = __expf(val[jt][r] - mrow[r]);
        rs[r] += p;
        pl[wid][(lhi * 4 + r) * 64 + jt * 16 + l15] = __float2bfloat16(p);
      }
#pragma unroll
    for (int r = 0; r < 4; ++r) {
      float v = rs[r];
      v += __shfl_xor(v, 1);
      v += __shfl_xor(v, 2);
      v += __shfl_xor(v, 4);
      v += __shfl_xor(v, 8);
      lrow[r] = lrow[r] * esc[r] + v;
    }
#pragma unroll
    for (int dt = 0; dt < 8; ++dt)
#pragma unroll
      for (int r = 0; r < 4; ++r) o[dt][r] *= esc[r];
    const short8 pa0 = *(const short8*)&pl[wid][l15 * 64 + lhi * 8];
    const short8 pa1 = *(const short8*)&pl[wid][l15 * 64 + 32 + lhi * 8];
#pragma unroll
    for (int dt = 0; dt < 8; ++dt) {
      const short8 bv0 = *(const short8*)&vt[(dt * 16 + l15) * 64 + lhi * 8];
      const short8 bv1 = *(const short8*)&vt[(dt * 16 + l15) * 64 + 32 + lhi * 8];
      o[dt] = __builtin_amdgcn_mfma_f32_16x16x32_bf16(pa0, bv0, o[dt], 0, 0, 0);
      o[dt] = __builtin_amdgcn_mfma_f32_16x16x32_bf16(pa1, bv1, o[dt], 0, 0, 0);
    }
  }
#pragma unroll
  for (int dt = 0; dt < 8; ++dt)
#pragma unroll
    for (int r = 0; r < 4; ++r) {
      const int i = q0 + wid * 16 + lhi * 4 + r;
      yb[(size_t)i * Cc + h * HD + dt * 16 + l15] =
          __float2bfloat16(o[dt][r] / lrow[r]);
    }
}

extern "C" void kernel_launch(void* const* d_in, const int* in_sizes, int n_in,
                              void* d_out, int out_size, void* d_ws,
                              size_t ws_size, hipStream_t stream) {
  const float* x = (const float*)d_in[0];
  const float* fc = (const float*)d_in[1];
  const float* Wa = (const float*)d_in[2];
  const float* Wp = (const float*)d_in[3];
  float* out = (float*)d_out;
  char* ws = (char*)d_ws;
  // workspace layout (60 MB total, overlapped lifetimes):
  //   phase 1 (cvt/tconv/gemm1): [xb 0..16 | Wat 16..28 | Wpt 28..36 | qkv 36..60]
  //   phase 2 (rope):            reads qkv 36..60, writes qb 0..16, kb 16..20, vb 20..24
  //   phase 3 (attn):            reads qb/kb/vb, writes yb over dead qkv 36..52
  //   phase 4 (gemm2):           reads yb + Wpt 28..36, writes d_out
  __hip_bfloat16* xb  = (__hip_bfloat16*)(ws);
  __hip_bfloat16* Wat = (__hip_bfloat16*)(ws + (16u << 20));
  __hip_bfloat16* Wpt = (__hip_bfloat16*)(ws + (28u << 20));
  __hip_bfloat16* qkv = (__hip_bfloat16*)(ws + (36u << 20));
  __hip_bfloat16* qb  = (__hip_bfloat16*)(ws);                 // over xb (dead)
  __hip_bfloat16* kb  = (__hip_bfloat16*)(ws + (16u << 20));   // over Wat (dead)
  __hip_bfloat16* vb  = (__hip_bfloat16*)(ws + (20u << 20));   // over Wat (dead)
  __hip_bfloat16* yb  = qkv;                                   // over qkv (dead)

  cvt4<<<dim3(Tt * Cc / 1024), 256, 0, stream>>>(x, xb, Tt * Cc);
  tconv<<<dim3(Cc / 32, QKVO / 32), dim3(32, 8), 0, stream>>>(Wa, Wat, Cc, QKVO);
  tconv<<<dim3(Cc / 32, Cc / 32), dim3(32, 8), 0, stream>>>(Wp, Wpt, Cc, Cc);
  gemm_bt<true><<<dim3(QKVO / 128, Tt / 128), 256, 0, stream>>>(
      xb, Wat, qkv, Tt, QKVO, Cc);
  rope_scatter<<<dim3(6, Tt), 256, 0, stream>>>(qkv, fc, qb, kb, vb);
  attn_band<<<dim3(Tt / 64, NH), 256, 0, stream>>>(qb, kb, vb, yb);
  gemm_bt<false><<<dim3(Cc / 128, Tt / 128), 256, 0, stream>>>(
      yb, Wpt, out, Tt, Cc, Cc);
}

// Round 6
// 463.317 us; speedup vs baseline: 1.6859x; 1.6859x over previous
//
#include <hip/hip_runtime.h>
#include <hip/hip_bf16.h>

typedef __attribute__((ext_vector_type(8))) short short8;
typedef __attribute__((ext_vector_type(4))) float f32x4;

static constexpr int Tt   = 4096;
static constexpr int Cc   = 2048;
static constexpr int NH   = 16;
static constexpr int HD   = 128;
static constexpr int QKVO = 3072;   // (16 + 2*4) * 128
static constexpr int W1   = 1023;   // WINDOW - 1

#define GLDS16(gp, lp)                                                        \
  __builtin_amdgcn_global_load_lds(                                           \
      (const __attribute__((address_space(1))) unsigned int*)(gp),            \
      (__attribute__((address_space(3))) unsigned int*)(lp), 16, 0, 0)

// ---------------- fp32 -> bf16 convert (vectorized) ----------------
__global__ void cvt4(const float* __restrict__ in,
                     __hip_bfloat16* __restrict__ out, int n) {
  int i = (blockIdx.x * blockDim.x + threadIdx.x) * 4;
  if (i >= n) return;
  float4 v = *(const float4*)&in[i];
  union { ushort4 u; __hip_bfloat16 b[4]; } o;
  o.b[0] = __float2bfloat16(v.x);
  o.b[1] = __float2bfloat16(v.y);
  o.b[2] = __float2bfloat16(v.z);
  o.b[3] = __float2bfloat16(v.w);
  *(ushort4*)&out[i] = o.u;
}

// ------------- transpose + convert: W[K][N] -> Wt[N][K] bf16 -------------
__global__ void tconv(const float* __restrict__ W,
                      __hip_bfloat16* __restrict__ Wt, int K, int N) {
  __shared__ float tile[32][33];
  const int k0 = blockIdx.x * 32, n0 = blockIdx.y * 32;
  const int tx = threadIdx.x, ty = threadIdx.y;  // 32 x 8
#pragma unroll
  for (int r = 0; r < 4; ++r)
    tile[ty * 4 + r][tx] = W[(size_t)(k0 + ty * 4 + r) * N + n0 + tx];
  __syncthreads();
#pragma unroll
  for (int r = 0; r < 4; ++r)
    Wt[(size_t)(n0 + ty * 4 + r) * K + k0 + tx] =
        __float2bfloat16(tile[tx][ty * 4 + r]);
}

// ---------------- bf16 GEMM: C[M][N] = A[M][K] * Bt[N][K]^T ----------------
template <bool OUT_BF16>
__global__ __launch_bounds__(256) void gemm_bt(
    const __hip_bfloat16* __restrict__ A, const __hip_bfloat16* __restrict__ Bt,
    void* __restrict__ Cout, int M, int N, int K) {
  __shared__ __hip_bfloat16 As[128 * 32];
  __shared__ __hip_bfloat16 Bs[128 * 32];
  const int tid = threadIdx.x;
  const int lane = tid & 63, wid = tid >> 6;
  const int l15 = lane & 15, lhi = lane >> 4;
  const int m0 = blockIdx.y * 128, n0 = blockIdx.x * 128;
  const int wm = wid >> 1, wn = wid & 1;
  f32x4 acc[4][4] = {};
  for (int k0 = 0; k0 < K; k0 += 32) {
#pragma unroll
    for (int cc = 0; cc < 2; ++cc) {
      const int ebase = cc * 2048 + wid * 512;  // wave-uniform elem base
      const int el = ebase + lane * 8;          // this lane's 8 elems
      const int row = el >> 5, col = el & 31;
      GLDS16(A + (size_t)(m0 + row) * K + k0 + col, As + ebase);
      GLDS16(Bt + (size_t)(n0 + row) * K + k0 + col, Bs + ebase);
    }
    __syncthreads();
    short8 af[4], bfr[4];
#pragma unroll
    for (int i = 0; i < 4; ++i)
      af[i] = *(const short8*)&As[(wm * 64 + i * 16 + l15) * 32 + lhi * 8];
#pragma unroll
    for (int j = 0; j < 4; ++j)
      bfr[j] = *(const short8*)&Bs[(wn * 64 + j * 16 + l15) * 32 + lhi * 8];
#pragma unroll
    for (int i = 0; i < 4; ++i)
#pragma unroll
      for (int j = 0; j < 4; ++j)
        acc[i][j] = __builtin_amdgcn_mfma_f32_16x16x32_bf16(af[i], bfr[j],
                                                            acc[i][j], 0, 0, 0);
    __syncthreads();
  }
#pragma unroll
  for (int i = 0; i < 4; ++i)
#pragma unroll
    for (int r = 0; r < 4; ++r) {
      const int row = m0 + wm * 64 + i * 16 + lhi * 4 + r;
#pragma unroll
      for (int j = 0; j < 4; ++j) {
        const int col = n0 + wn * 64 + j * 16 + l15;
        if (OUT_BF16)
          ((__hip_bfloat16*)Cout)[(size_t)row * N + col] =
              __float2bfloat16(acc[i][j][r]);
        else
          ((float*)Cout)[(size_t)row * N + col] = acc[i][j][r];
      }
    }
}

// ------- RoPE + scramble-scatter: qkv[t][c] -> qb[t'][h*128+d], kb, vb -------
__global__ void rope_scatter(const __hip_bfloat16* __restrict__ qkv,
                             const float* __restrict__ fc,
                             __hip_bfloat16* __restrict__ qb,
                             __hip_bfloat16* __restrict__ kb,
                             __hip_bfloat16* __restrict__ vb) {
  const int p = blockIdx.x * blockDim.x + threadIdx.x;  // 0..1535
  const int t = blockIdx.y;
  const int c = p * 2;
  const int kv = c / 768;
  const int rem = c - kv * 768;
  const int slot = rem >> 7;
  const int d = rem & 127;
  const ushort2 xy = *(const ushort2*)&qkv[(size_t)t * QKVO + c];
  const float x0 = __bfloat162float(*(const __hip_bfloat16*)&xy.x);
  const float x1 = __bfloat162float(*(const __hip_bfloat16*)&xy.y);
  union { ushort2 uu; __hip_bfloat16 b[2]; } o;
  if (slot < 4) {
    const unsigned u = ((unsigned)kv << 14) | ((unsigned)slot << 12) | (unsigned)t;
    const int tp = u >> 4, h = u & 15;
    const float2 cs = *(const float2*)&fc[(size_t)tp * 128 + (d >> 1) * 2];
    o.b[0] = __float2bfloat16(x0 * cs.x - x1 * cs.y);
    o.b[1] = __float2bfloat16(x1 * cs.x + x0 * cs.y);
    *(ushort2*)&qb[(size_t)tp * Cc + h * HD + d] = o.uu;
  } else {
    const unsigned u2 = ((unsigned)kv << 12) | (unsigned)t;
    const int tp = u2 >> 2, hk = u2 & 3;
    if (slot == 4) {
      const float2 cs = *(const float2*)&fc[(size_t)tp * 128 + (d >> 1) * 2];
      o.b[0] = __float2bfloat16(x0 * cs.x - x1 * cs.y);
      o.b[1] = __float2bfloat16(x1 * cs.x + x0 * cs.y);
      *(ushort2*)&kb[(size_t)tp * 512 + hk * HD + d] = o.uu;
    } else {
      o.uu = xy;
      *(ushort2*)&vb[(size_t)tp * 512 + hk * HD + d] = o.uu;
    }
  }
}

// ------------- banded GQA flash attention (QBLK=128, KVBLK=64, 8 waves) -----
// All LDS tiles XOR-swizzled (byte ^= (row&7)<<4) to kill bank conflicts:
//  - kt staged via global_load_lds with PRE-SWIZZLED global source (linear dest)
//  - vt transposed on the GLOBAL-read side (coalesced ushort gathers), written
//    as swizzled 16B ds_write_b128 (no scalar LDS writes)
//  - pl (P round-trip) swizzled on both sides
__global__ __launch_bounds__(512) void attn_band(
    const __hip_bfloat16* __restrict__ qb, const __hip_bfloat16* __restrict__ kb,
    const __hip_bfloat16* __restrict__ vb, __hip_bfloat16* __restrict__ yb) {
  __shared__ __hip_bfloat16 kt[64 * 128];   // [j][d], 256B rows, swizzled
  __shared__ __hip_bfloat16 vt[128 * 64];   // [d][j], 128B rows, swizzled
  __shared__ __hip_bfloat16 pl[8][16 * 64]; // per-wave, 128B rows, swizzled
  const int tid = threadIdx.x, lane = tid & 63, wid = tid >> 6;
  const int l15 = lane & 15, lhi = lane >> 4;
  const int q0 = blockIdx.x * 128, h = blockIdx.y;
  const int kvh = h >> 2;
  const int qrow = q0 + wid * 16 + l15;
  short8 aq[4];
#pragma unroll
  for (int kc = 0; kc < 4; ++kc)
    aq[kc] = *(const short8*)&qb[(size_t)qrow * Cc + h * HD + kc * 32 + lhi * 8];
  f32x4 o[8] = {};
  float mrow[4] = {-1e30f, -1e30f, -1e30f, -1e30f};
  float lrow[4] = {0.f, 0.f, 0.f, 0.f};
  const int js = (q0 - W1 > 0 ? q0 - W1 : 0) & ~63;
  const int jeu = q0 + 128 + W1;
  const int je = jeu < Tt ? jeu : Tt;
  const float scale = 0.08838834764831845f;  // 1/sqrt(128)
  char* ktc = (char*)kt;
  char* vtc = (char*)vt;
  char* plc = (char*)&pl[wid][0];
  for (int j0 = js; j0 < je; j0 += 64) {
    __syncthreads();
    // ---- K stage: 2 global_load_lds per wave, pre-swizzled source ----
#pragma unroll
    for (int cc = 0; cc < 2; ++cc) {
      const int sb = (cc * 8 + wid) << 10;          // wave-uniform LDS byte base
      const int S = sb + lane * 16;                 // this lane's dest slot
      const int row = S >> 8;                       // 0..63
      const int colb = (S & 255) ^ ((row & 7) << 4);
      int jc = j0 + row;
      jc = jc < Tt - 1 ? jc : Tt - 1;
      GLDS16(kb + (size_t)jc * 512 + kvh * HD + (colb >> 1), ktc + sb);
    }
    // ---- V stage: transpose on global read, swizzled 16B LDS writes ----
#pragma unroll
    for (int it = 0; it < 2; ++it) {
      const int d = tid & 127;
      const int jg = (tid >> 7) + it * 4;           // 0..7
      union { short8 v8; unsigned short u[8]; } pk;
#pragma unroll
      for (int q = 0; q < 8; ++q) {
        int jc = j0 + jg * 8 + q;
        jc = jc < Tt - 1 ? jc : Tt - 1;
        pk.u[q] = *(const unsigned short*)&vb[(size_t)jc * 512 + kvh * HD + d];
      }
      const int vbyt = (d * 128 + jg * 16) ^ ((d & 7) << 4);
      *(short8*)(vtc + vbyt) = pk.v8;
    }
    __syncthreads();
    // ---- QK^T ----
    f32x4 s[4] = {};
#pragma unroll
    for (int jt = 0; jt < 4; ++jt) {
      const int row = jt * 16 + l15;
      const int sw = (row & 7) << 4;
#pragma unroll
      for (int kc = 0; kc < 4; ++kc) {
        const short8 bk =
            *(const short8*)(ktc + row * 256 + ((kc * 64 + lhi * 16) ^ sw));
        s[jt] = __builtin_amdgcn_mfma_f32_16x16x32_bf16(aq[kc], bk, s[jt], 0, 0, 0);
      }
    }
    // ---- mask + online softmax ----
    float val[4][4], pm[4];
#pragma unroll
    for (int jt = 0; jt < 4; ++jt)
#pragma unroll
      for (int r = 0; r < 4; ++r) {
        const int j = j0 + jt * 16 + l15;
        const int i = q0 + wid * 16 + lhi * 4 + r;
        const int diff = i > j ? i - j : j - i;
        const bool ok = (j < Tt) && (diff <= W1);
        val[jt][r] = ok ? s[jt][r] * scale : -1e30f;
      }
#pragma unroll
    for (int r = 0; r < 4; ++r) {
      float v = fmaxf(fmaxf(val[0][r], val[1][r]), fmaxf(val[2][r], val[3][r]));
      v = fmaxf(v, __shfl_xor(v, 1));
      v = fmaxf(v, __shfl_xor(v, 2));
      v = fmaxf(v, __shfl_xor(v, 4));
      v = fmaxf(v, __shfl_xor(v, 8));
      pm[r] = v;
    }
    float esc[4];
#pragma unroll
    for (int r = 0; r < 4; ++r) {
      const float mn = fmaxf(mrow[r], pm[r]);
      esc[r] = __expf(mrow[r] - mn);
      mrow[r] = mn;
    }
    float rs[4] = {0.f, 0.f, 0.f, 0.f};
#pragma unroll
    for (int jt = 0; jt < 4; ++jt)
#pragma unroll
      for (int r = 0; r < 4; ++r) {
        const float p = __expf(val[jt][r] - mrow[r]);
        rs[r] += p;
        const int row = lhi * 4 + r;
        const int b = row * 128 + (((jt * 16 + l15) * 2) ^ ((row & 7) << 4));
        *(__hip_bfloat16*)(plc + b) = __float2bfloat16(p);
      }
#pragma unroll
    for (int r = 0; r < 4; ++r) {
      float v = rs[r];
      v += __shfl_xor(v, 1);
      v += __shfl_xor(v, 2);
      v += __shfl_xor(v, 4);
      v += __shfl_xor(v, 8);
      lrow[r] = lrow[r] * esc[r] + v;
    }
#pragma unroll
    for (int dt = 0; dt < 8; ++dt)
#pragma unroll
      for (int r = 0; r < 4; ++r) o[dt][r] *= esc[r];
    // ---- PV ----
    const int psw = (l15 & 7) << 4;
    const short8 pa0 = *(const short8*)(plc + l15 * 128 + ((lhi * 16) ^ psw));
    const short8 pa1 = *(const short8*)(plc + l15 * 128 + ((64 + lhi * 16) ^ psw));
#pragma unroll
    for (int dt = 0; dt < 8; ++dt) {
      const int d = dt * 16 + l15;
      const int vsw = (d & 7) << 4;
      const short8 bv0 = *(const short8*)(vtc + d * 128 + ((lhi * 16) ^ vsw));
      const short8 bv1 = *(const short8*)(vtc + d * 128 + ((64 + lhi * 16) ^ vsw));
      o[dt] = __builtin_amdgcn_mfma_f32_16x16x32_bf16(pa0, bv0, o[dt], 0, 0, 0);
      o[dt] = __builtin_amdgcn_mfma_f32_16x16x32_bf16(pa1, bv1, o[dt], 0, 0, 0);
    }
  }
#pragma unroll
  for (int dt = 0; dt < 8; ++dt)
#pragma unroll
    for (int r = 0; r < 4; ++r) {
      const int i = q0 + wid * 16 + lhi * 4 + r;
      yb[(size_t)i * Cc + h * HD + dt * 16 + l15] =
          __float2bfloat16(o[dt][r] / lrow[r]);
    }
}

extern "C" void kernel_launch(void* const* d_in, const int* in_sizes, int n_in,
                              void* d_out, int out_size, void* d_ws,
                              size_t ws_size, hipStream_t stream) {
  const float* x = (const float*)d_in[0];
  const float* fc = (const float*)d_in[1];
  const float* Wa = (const float*)d_in[2];
  const float* Wp = (const float*)d_in[3];
  float* out = (float*)d_out;
  char* ws = (char*)d_ws;
  // workspace layout (60 MB total, overlapped lifetimes):
  __hip_bfloat16* xb  = (__hip_bfloat16*)(ws);
  __hip_bfloat16* Wat = (__hip_bfloat16*)(ws + (16u << 20));
  __hip_bfloat16* Wpt = (__hip_bfloat16*)(ws + (28u << 20));
  __hip_bfloat16* qkv = (__hip_bfloat16*)(ws + (36u << 20));
  __hip_bfloat16* qb  = (__hip_bfloat16*)(ws);                 // over xb (dead)
  __hip_bfloat16* kb  = (__hip_bfloat16*)(ws + (16u << 20));   // over Wat (dead)
  __hip_bfloat16* vb  = (__hip_bfloat16*)(ws + (20u << 20));   // over Wat (dead)
  __hip_bfloat16* yb  = qkv;                                   // over qkv (dead)

  cvt4<<<dim3(Tt * Cc / 1024), 256, 0, stream>>>(x, xb, Tt * Cc);
  tconv<<<dim3(Cc / 32, QKVO / 32), dim3(32, 8), 0, stream>>>(Wa, Wat, Cc, QKVO);
  tconv<<<dim3(Cc / 32, Cc / 32), dim3(32, 8), 0, stream>>>(Wp, Wpt, Cc, Cc);
  gemm_bt<true><<<dim3(QKVO / 128, Tt / 128), 256, 0, stream>>>(
      xb, Wat, qkv, Tt, QKVO, Cc);
  rope_scatter<<<dim3(6, Tt), 256, 0, stream>>>(qkv, fc, qb, kb, vb);
  attn_band<<<dim3(Tt / 128, NH), 512, 0, stream>>>(qb, kb, vb, yb);
  gemm_bt<false><<<dim3(Cc / 128, Tt / 128), 256, 0, stream>>>(
      yb, Wpt, out, Tt, Cc, Cc);
}

// Round 8
// 460.010 us; speedup vs baseline: 1.6980x; 1.0072x over previous
//
#include <hip/hip_runtime.h>
#include <hip/hip_bf16.h>

typedef __attribute__((ext_vector_type(8))) short short8;
typedef __attribute__((ext_vector_type(4))) float f32x4;

static constexpr int Tt   = 4096;
static constexpr int Cc   = 2048;
static constexpr int NH   = 16;
static constexpr int HD   = 128;
static constexpr int QKVO = 3072;   // (16 + 2*4) * 128
static constexpr int W1   = 1023;   // WINDOW - 1

#define GLDS16(gp, lp)                                                        \
  __builtin_amdgcn_global_load_lds(                                           \
      (const __attribute__((address_space(1))) unsigned int*)(gp),            \
      (__attribute__((address_space(3))) unsigned int*)(lp), 16, 0, 0)

// ---------------- fp32 -> bf16 convert (vectorized) ----------------
__global__ void cvt4(const float* __restrict__ in,
                     __hip_bfloat16* __restrict__ out, int n) {
  int i = (blockIdx.x * blockDim.x + threadIdx.x) * 4;
  if (i >= n) return;
  float4 v = *(const float4*)&in[i];
  union { ushort4 u; __hip_bfloat16 b[4]; } o;
  o.b[0] = __float2bfloat16(v.x);
  o.b[1] = __float2bfloat16(v.y);
  o.b[2] = __float2bfloat16(v.z);
  o.b[3] = __float2bfloat16(v.w);
  *(ushort4*)&out[i] = o.u;
}

// ------------- transpose + convert: W[K][N] -> Wt[N][K] bf16 -------------
__global__ void tconv(const float* __restrict__ W,
                      __hip_bfloat16* __restrict__ Wt, int K, int N) {
  __shared__ float tile[32][33];
  const int k0 = blockIdx.x * 32, n0 = blockIdx.y * 32;
  const int tx = threadIdx.x, ty = threadIdx.y;  // 32 x 8
#pragma unroll
  for (int r = 0; r < 4; ++r)
    tile[ty * 4 + r][tx] = W[(size_t)(k0 + ty * 4 + r) * N + n0 + tx];
  __syncthreads();
#pragma unroll
  for (int r = 0; r < 4; ++r)
    Wt[(size_t)(n0 + ty * 4 + r) * K + k0 + tx] =
        __float2bfloat16(tile[tx][ty * 4 + r]);
}

// ------------- bf16 transpose: vb[T][512] -> vbt[4][128][T] -------------
__global__ void vtrans(const __hip_bfloat16* __restrict__ vb,
                       __hip_bfloat16* __restrict__ vbt) {
  __shared__ unsigned short tile[32][34];
  const int t0 = blockIdx.x * 32, d0 = blockIdx.y * 32, kvh = blockIdx.z;
  const int tx = threadIdx.x, ty = threadIdx.y;  // 32 x 8
#pragma unroll
  for (int r = 0; r < 4; ++r)
    tile[ty * 4 + r][tx] =
        *(const unsigned short*)&vb[(size_t)(t0 + ty * 4 + r) * 512 +
                                    kvh * HD + d0 + tx];
  __syncthreads();
#pragma unroll
  for (int r = 0; r < 4; ++r)
    *(unsigned short*)&vbt[(size_t)kvh * 524288 + (size_t)(d0 + ty * 4 + r) * Tt +
                           t0 + tx] = tile[tx][ty * 4 + r];
}

// ---------------- bf16 GEMM: C[M][N] = A[M][K] * Bt[N][K]^T ----------------
template <bool OUT_BF16>
__global__ __launch_bounds__(256) void gemm_bt(
    const __hip_bfloat16* __restrict__ A, const __hip_bfloat16* __restrict__ Bt,
    void* __restrict__ Cout, int M, int N, int K) {
  __shared__ __hip_bfloat16 As[128 * 32];
  __shared__ __hip_bfloat16 Bs[128 * 32];
  const int tid = threadIdx.x;
  const int lane = tid & 63, wid = tid >> 6;
  const int l15 = lane & 15, lhi = lane >> 4;
  const int m0 = blockIdx.y * 128, n0 = blockIdx.x * 128;
  const int wm = wid >> 1, wn = wid & 1;
  f32x4 acc[4][4] = {};
  for (int k0 = 0; k0 < K; k0 += 32) {
#pragma unroll
    for (int cc = 0; cc < 2; ++cc) {
      const int ebase = cc * 2048 + wid * 512;  // wave-uniform elem base
      const int el = ebase + lane * 8;          // this lane's 8 elems
      const int row = el >> 5, col = el & 31;
      GLDS16(A + (size_t)(m0 + row) * K + k0 + col, As + ebase);
      GLDS16(Bt + (size_t)(n0 + row) * K + k0 + col, Bs + ebase);
    }
    __syncthreads();
    short8 af[4], bfr[4];
#pragma unroll
    for (int i = 0; i < 4; ++i)
      af[i] = *(const short8*)&As[(wm * 64 + i * 16 + l15) * 32 + lhi * 8];
#pragma unroll
    for (int j = 0; j < 4; ++j)
      bfr[j] = *(const short8*)&Bs[(wn * 64 + j * 16 + l15) * 32 + lhi * 8];
#pragma unroll
    for (int i = 0; i < 4; ++i)
#pragma unroll
      for (int j = 0; j < 4; ++j)
        acc[i][j] = __builtin_amdgcn_mfma_f32_16x16x32_bf16(af[i], bfr[j],
                                                            acc[i][j], 0, 0, 0);
    __syncthreads();
  }
#pragma unroll
  for (int i = 0; i < 4; ++i)
#pragma unroll
    for (int r = 0; r < 4; ++r) {
      const int row = m0 + wm * 64 + i * 16 + lhi * 4 + r;
#pragma unroll
      for (int j = 0; j < 4; ++j) {
        const int col = n0 + wn * 64 + j * 16 + l15;
        if (OUT_BF16)
          ((__hip_bfloat16*)Cout)[(size_t)row * N + col] =
              __float2bfloat16(acc[i][j][r]);
        else
          ((float*)Cout)[(size_t)row * N + col] = acc[i][j][r];
      }
    }
}

// ------- RoPE + scramble-scatter: qkv[t][c] -> qb[t'][h*128+d], kb, vb -------
__global__ void rope_scatter(const __hip_bfloat16* __restrict__ qkv,
                             const float* __restrict__ fc,
                             __hip_bfloat16* __restrict__ qb,
                             __hip_bfloat16* __restrict__ kb,
                             __hip_bfloat16* __restrict__ vb) {
  const int p = blockIdx.x * blockDim.x + threadIdx.x;  // 0..1535
  const int t = blockIdx.y;
  const int c = p * 2;
  const int kv = c / 768;
  const int rem = c - kv * 768;
  const int slot = rem >> 7;
  const int d = rem & 127;
  const ushort2 xy = *(const ushort2*)&qkv[(size_t)t * QKVO + c];
  const float x0 = __bfloat162float(*(const __hip_bfloat16*)&xy.x);
  const float x1 = __bfloat162float(*(const __hip_bfloat16*)&xy.y);
  union { ushort2 uu; __hip_bfloat16 b[2]; } o;
  if (slot < 4) {
    const unsigned u = ((unsigned)kv << 14) | ((unsigned)slot << 12) | (unsigned)t;
    const int tp = u >> 4, h = u & 15;
    const float2 cs = *(const float2*)&fc[(size_t)tp * 128 + (d >> 1) * 2];
    o.b[0] = __float2bfloat16(x0 * cs.x - x1 * cs.y);
    o.b[1] = __float2bfloat16(x1 * cs.x + x0 * cs.y);
    *(ushort2*)&qb[(size_t)tp * Cc + h * HD + d] = o.uu;
  } else {
    const unsigned u2 = ((unsigned)kv << 12) | (unsigned)t;
    const int tp = u2 >> 2, hk = u2 & 3;
    if (slot == 4) {
      const float2 cs = *(const float2*)&fc[(size_t)tp * 128 + (d >> 1) * 2];
      o.b[0] = __float2bfloat16(x0 * cs.x - x1 * cs.y);
      o.b[1] = __float2bfloat16(x1 * cs.x + x0 * cs.y);
      *(ushort2*)&kb[(size_t)tp * 512 + hk * HD + d] = o.uu;
    } else {
      o.uu = xy;
      *(ushort2*)&vb[(size_t)tp * 512 + hk * HD + d] = o.uu;
    }
  }
}

// --- banded GQA flash attention (QBLK=128, KVBLK=64, 8 waves, 2-phase dbuf) --
// K and V^T both staged via global_load_lds with pre-swizzled global sources
// (linear LDS dest, rule #21); double-buffered with ONE barrier per tile so
// next-tile loads overlap current-tile compute; defer-max (THR=8) skips the
// O-rescale when the running max doesn't grow.
__global__ __launch_bounds__(512) void attn_band(
    const __hip_bfloat16* __restrict__ qb, const __hip_bfloat16* __restrict__ kb,
    const __hip_bfloat16* __restrict__ vbt, __hip_bfloat16* __restrict__ yb) {
  __shared__ __hip_bfloat16 kt[2][64 * 128];   // [j][d], swizzled
  __shared__ __hip_bfloat16 vt[2][128 * 64];   // [d][j], swizzled
  __shared__ __hip_bfloat16 pl[8][16 * 64];    // per-wave P round-trip, swizzled
  const int tid = threadIdx.x, lane = tid & 63, wid = tid >> 6;
  const int l15 = lane & 15, lhi = lane >> 4;
  const int q0 = blockIdx.x * 128, h = blockIdx.y;
  const int kvh = h >> 2;
  const int qrow = q0 + wid * 16 + l15;
  short8 aq[4];
#pragma unroll
  for (int kc = 0; kc < 4; ++kc)
    aq[kc] = *(const short8*)&qb[(size_t)qrow * Cc + h * HD + kc * 32 + lhi * 8];
  f32x4 o[8] = {};
  float mrow[4] = {-1e30f, -1e30f, -1e30f, -1e30f};
  float lrow[4] = {0.f, 0.f, 0.f, 0.f};
  const int js = (q0 - W1 > 0 ? q0 - W1 : 0) & ~63;
  const int jeu = q0 + 128 + W1;
  const int je = jeu < Tt ? jeu : Tt;
  const int nt = (je - js + 63) >> 6;
  const float scale = 0.08838834764831845f;  // 1/sqrt(128)
  char* ktb = (char*)kt;
  char* vtb = (char*)vt;
  char* plc = (char*)&pl[wid][0];
  const size_t vbase = (size_t)kvh * 524288;

  // ---- staging: 2 glds for K-tile + 2 for V^T-tile per wave ----
  auto stage = [&](int j0, int buf) {
    char* kd = ktb + buf * 16384;
    char* vd = vtb + buf * 16384;
#pragma unroll
    for (int cc = 0; cc < 2; ++cc) {
      const int sb = (cc * 8 + wid) << 10;
      {  // K: dest rows are j (256B rows)
        const int S = sb + lane * 16;
        const int row = S >> 8;
        const int colb = (S & 255) ^ ((row & 7) << 4);
        int jc = j0 + row;
        jc = jc < Tt - 1 ? jc : Tt - 1;
        GLDS16(kb + (size_t)jc * 512 + kvh * HD + (colb >> 1), kd + sb);
      }
      {  // V^T: dest rows are d (128B rows)
        const int S = sb + lane * 16;
        const int row = S >> 7;
        const int colb = (S & 127) ^ ((row & 7) << 4);
        GLDS16(vbt + vbase + (size_t)row * Tt + j0 + (colb >> 1), vd + sb);
      }
    }
  };

  stage(js, 0);
  int cur = 0;
  for (int t = 0; t < nt; ++t) {
    const int j0 = js + t * 64;
    __syncthreads();  // drains vmcnt: buf[cur] staged; buf[cur^1] free
    if (t + 1 < nt) stage(j0 + 64, cur ^ 1);
    char* ktc = ktb + cur * 16384;
    char* vtc = vtb + cur * 16384;
    // ---- QK^T ----
    f32x4 s[4] = {};
#pragma unroll
    for (int jt = 0; jt < 4; ++jt) {
      const int row = jt * 16 + l15;
      const int sw = (row & 7) << 4;
#pragma unroll
      for (int kc = 0; kc < 4; ++kc) {
        const short8 bk =
            *(const short8*)(ktc + row * 256 + ((kc * 64 + lhi * 16) ^ sw));
        s[jt] = __builtin_amdgcn_mfma_f32_16x16x32_bf16(aq[kc], bk, s[jt], 0, 0, 0);
      }
    }
    // ---- mask + online softmax (defer-max, THR=8) ----
    float val[4][4], pm[4];
#pragma unroll
    for (int jt = 0; jt < 4; ++jt)
#pragma unroll
      for (int r = 0; r < 4; ++r) {
        const int j = j0 + jt * 16 + l15;
        const int i = q0 + wid * 16 + lhi * 4 + r;
        const int diff = i > j ? i - j : j - i;
        const bool ok = (j < Tt) && (diff <= W1);
        val[jt][r] = ok ? s[jt][r] * scale : -1e30f;
      }
#pragma unroll
    for (int r = 0; r < 4; ++r) {
      float v = fmaxf(fmaxf(val[0][r], val[1][r]), fmaxf(val[2][r], val[3][r]));
      v = fmaxf(v, __shfl_xor(v, 1));
      v = fmaxf(v, __shfl_xor(v, 2));
      v = fmaxf(v, __shfl_xor(v, 4));
      v = fmaxf(v, __shfl_xor(v, 8));
      pm[r] = v;
    }
    float need = 0.f;
#pragma unroll
    for (int r = 0; r < 4; ++r) need = fmaxf(need, pm[r] - mrow[r]);
    if (!__all(need <= 8.0f)) {
#pragma unroll
      for (int r = 0; r < 4; ++r) {
        const float mn = fmaxf(mrow[r], pm[r]);
        const float esc = __expf(mrow[r] - mn);
        mrow[r] = mn;
        lrow[r] *= esc;
#pragma unroll
        for (int dt = 0; dt < 8; ++dt) o[dt][r] *= esc;
      }
    }
    float rs[4] = {0.f, 0.f, 0.f, 0.f};
#pragma unroll
    for (int jt = 0; jt < 4; ++jt)
#pragma unroll
      for (int r = 0; r < 4; ++r) {
        const float p = __expf(val[jt][r] - mrow[r]);
        rs[r] += p;
        const int row = lhi * 4 + r;
        const int b = row * 128 + (((jt * 16 + l15) * 2) ^ ((row & 7) << 4));
        *(__hip_bfloat16*)(plc + b) = __float2bfloat16(p);
      }
#pragma unroll
    for (int r = 0; r < 4; ++r) {
      float v = rs[r];
      v += __shfl_xor(v, 1);
      v += __shfl_xor(v, 2);
      v += __shfl_xor(v, 4);
      v += __shfl_xor(v, 8);
      lrow[r] += v;
    }
    // ---- PV ----
    const int psw = (l15 & 7) << 4;
    const short8 pa0 = *(const short8*)(plc + l15 * 128 + ((lhi * 16) ^ psw));
    const short8 pa1 = *(const short8*)(plc + l15 * 128 + ((64 + lhi * 16) ^ psw));
#pragma unroll
    for (int dt = 0; dt < 8; ++dt) {
      const int d = dt * 16 + l15;
      const int vsw = (d & 7) << 4;
      const short8 bv0 = *(const short8*)(vtc + d * 128 + ((lhi * 16) ^ vsw));
      const short8 bv1 = *(const short8*)(vtc + d * 128 + ((64 + lhi * 16) ^ vsw));
      o[dt] = __builtin_amdgcn_mfma_f32_16x16x32_bf16(pa0, bv0, o[dt], 0, 0, 0);
      o[dt] = __builtin_amdgcn_mfma_f32_16x16x32_bf16(pa1, bv1, o[dt], 0, 0, 0);
    }
    cur ^= 1;
  }
#pragma unroll
  for (int dt = 0; dt < 8; ++dt)
#pragma unroll
    for (int r = 0; r < 4; ++r) {
      const int i = q0 + wid * 16 + lhi * 4 + r;
      yb[(size_t)i * Cc + h * HD + dt * 16 + l15] =
          __float2bfloat16(o[dt][r] / lrow[r]);
    }
}

extern "C" void kernel_launch(void* const* d_in, const int* in_sizes, int n_in,
                              void* d_out, int out_size, void* d_ws,
                              size_t ws_size, hipStream_t stream) {
  const float* x = (const float*)d_in[0];
  const float* fc = (const float*)d_in[1];
  const float* Wa = (const float*)d_in[2];
  const float* Wp = (const float*)d_in[3];
  float* out = (float*)d_out;
  char* ws = (char*)d_ws;
  // workspace layout (60 MB total, overlapped lifetimes):
  //  phase1: xb 0..16 | Wat 16..28 | Wpt 28..36 | qkv 36..60
  //  phase2 (rope):   qb 0..16, kb 16..20, vb 20..24   (over xb/Wat, dead)
  //  phase2b (vtrans): vbt 24..28 (over Wat tail, dead; vb still live)
  //  phase3 (attn):   reads qb/kb/vbt, writes yb 36..52 (over qkv, dead)
  //  phase4 (gemm2):  reads yb + Wpt, writes d_out
  __hip_bfloat16* xb  = (__hip_bfloat16*)(ws);
  __hip_bfloat16* Wat = (__hip_bfloat16*)(ws + (16u << 20));
  __hip_bfloat16* Wpt = (__hip_bfloat16*)(ws + (28u << 20));
  __hip_bfloat16* qkv = (__hip_bfloat16*)(ws + (36u << 20));
  __hip_bfloat16* qb  = (__hip_bfloat16*)(ws);
  __hip_bfloat16* kb  = (__hip_bfloat16*)(ws + (16u << 20));
  __hip_bfloat16* vb  = (__hip_bfloat16*)(ws + (20u << 20));
  __hip_bfloat16* vbt = (__hip_bfloat16*)(ws + (24u << 20));
  __hip_bfloat16* yb  = qkv;

  cvt4<<<dim3(Tt * Cc / 1024), 256, 0, stream>>>(x, xb, Tt * Cc);
  tconv<<<dim3(Cc / 32, QKVO / 32), dim3(32, 8), 0, stream>>>(Wa, Wat, Cc, QKVO);
  tconv<<<dim3(Cc / 32, Cc / 32), dim3(32, 8), 0, stream>>>(Wp, Wpt, Cc, Cc);
  gemm_bt<true><<<dim3(QKVO / 128, Tt / 128), 256, 0, stream>>>(
      xb, Wat, qkv, Tt, QKVO, Cc);
  rope_scatter<<<dim3(6, Tt), 256, 0, stream>>>(qkv, fc, qb, kb, vb);
  vtrans<<<dim3(Tt / 32, HD / 32, 4), dim3(32, 8), 0, stream>>>(vb, vbt);
  attn_band<<<dim3(Tt / 128, NH), 512, 0, stream>>>(qb, kb, vbt, yb);
  gemm_bt<false><<<dim3(Cc / 128, Tt / 128), 256, 0, stream>>>(
      yb, Wpt, out, Tt, Cc, Cc);
}

// Round 12
// 414.966 us; speedup vs baseline: 1.8824x; 1.1086x over previous
//
#include <hip/hip_runtime.h>
#include <hip/hip_bf16.h>

typedef __attribute__((ext_vector_type(8))) short short8;
typedef __attribute__((ext_vector_type(4))) float f32x4;

static constexpr int Tt   = 4096;
static constexpr int Cc   = 2048;
static constexpr int NH   = 16;
static constexpr int HD   = 128;
static constexpr int QKVO = 3072;   // (16 + 2*4) * 128
static constexpr int W1   = 1023;   // WINDOW - 1

#define GLDS16(gp, lp)                                                        \
  __builtin_amdgcn_global_load_lds(                                           \
      (const __attribute__((address_space(1))) unsigned int*)(gp),            \
      (__attribute__((address_space(3))) unsigned int*)(lp), 16, 0, 0)

// ---------------- fp32 -> bf16 convert (vectorized) ----------------
__global__ void cvt4(const float* __restrict__ in,
                     __hip_bfloat16* __restrict__ out, int n) {
  int i = (blockIdx.x * blockDim.x + threadIdx.x) * 4;
  if (i >= n) return;
  float4 v = *(const float4*)&in[i];
  union { ushort4 u; __hip_bfloat16 b[4]; } o;
  o.b[0] = __float2bfloat16(v.x);
  o.b[1] = __float2bfloat16(v.y);
  o.b[2] = __float2bfloat16(v.z);
  o.b[3] = __float2bfloat16(v.w);
  *(ushort4*)&out[i] = o.u;
}

// ------------- transpose + convert: W[K][N] -> Wt[N][K] bf16 -------------
__global__ void tconv(const float* __restrict__ W,
                      __hip_bfloat16* __restrict__ Wt, int K, int N) {
  __shared__ float tile[32][33];
  const int k0 = blockIdx.x * 32, n0 = blockIdx.y * 32;
  const int tx = threadIdx.x, ty = threadIdx.y;  // 32 x 8
#pragma unroll
  for (int r = 0; r < 4; ++r)
    tile[ty * 4 + r][tx] = W[(size_t)(k0 + ty * 4 + r) * N + n0 + tx];
  __syncthreads();
#pragma unroll
  for (int r = 0; r < 4; ++r)
    Wt[(size_t)(n0 + ty * 4 + r) * K + k0 + tx] =
        __float2bfloat16(tile[tx][ty * 4 + r]);
}

// ------------- bf16 transpose: vb[T][512] -> vbt[4][128][T] -------------
__global__ void vtrans(const __hip_bfloat16* __restrict__ vb,
                       __hip_bfloat16* __restrict__ vbt) {
  __shared__ unsigned short tile[32][34];
  const int t0 = blockIdx.x * 32, d0 = blockIdx.y * 32, kvh = blockIdx.z;
  const int tx = threadIdx.x, ty = threadIdx.y;  // 32 x 8
#pragma unroll
  for (int r = 0; r < 4; ++r)
    tile[ty * 4 + r][tx] =
        *(const unsigned short*)&vb[(size_t)(t0 + ty * 4 + r) * 512 +
                                    kvh * HD + d0 + tx];
  __syncthreads();
#pragma unroll
  for (int r = 0; r < 4; ++r)
    *(unsigned short*)&vbt[(size_t)kvh * 524288 + (size_t)(d0 + ty * 4 + r) * Tt +
                           t0 + tx] = tile[tx][ty * 4 + r];
}

// ---------------- bf16 GEMM: C[M][N] = A[M][K] * Bt[N][K]^T ----------------
template <bool OUT_BF16>
__global__ __launch_bounds__(256) void gemm_bt(
    const __hip_bfloat16* __restrict__ A, const __hip_bfloat16* __restrict__ Bt,
    void* __restrict__ Cout, int M, int N, int K) {
  __shared__ __hip_bfloat16 As[128 * 32];
  __shared__ __hip_bfloat16 Bs[128 * 32];
  const int tid = threadIdx.x;
  const int lane = tid & 63, wid = tid >> 6;
  const int l15 = lane & 15, lhi = lane >> 4;
  const int m0 = blockIdx.y * 128, n0 = blockIdx.x * 128;
  const int wm = wid >> 1, wn = wid & 1;
  f32x4 acc[4][4] = {};
  for (int k0 = 0; k0 < K; k0 += 32) {
#pragma unroll
    for (int cc = 0; cc < 2; ++cc) {
      const int ebase = cc * 2048 + wid * 512;  // wave-uniform elem base
      const int el = ebase + lane * 8;          // this lane's 8 elems
      const int row = el >> 5, col = el & 31;
      GLDS16(A + (size_t)(m0 + row) * K + k0 + col, As + ebase);
      GLDS16(Bt + (size_t)(n0 + row) * K + k0 + col, Bs + ebase);
    }
    __syncthreads();
    short8 af[4], bfr[4];
#pragma unroll
    for (int i = 0; i < 4; ++i)
      af[i] = *(const short8*)&As[(wm * 64 + i * 16 + l15) * 32 + lhi * 8];
#pragma unroll
    for (int j = 0; j < 4; ++j)
      bfr[j] = *(const short8*)&Bs[(wn * 64 + j * 16 + l15) * 32 + lhi * 8];
#pragma unroll
    for (int i = 0; i < 4; ++i)
#pragma unroll
      for (int j = 0; j < 4; ++j)
        acc[i][j] = __builtin_amdgcn_mfma_f32_16x16x32_bf16(af[i], bfr[j],
                                                            acc[i][j], 0, 0, 0);
    __syncthreads();
  }
#pragma unroll
  for (int i = 0; i < 4; ++i)
#pragma unroll
    for (int r = 0; r < 4; ++r) {
      const int row = m0 + wm * 64 + i * 16 + lhi * 4 + r;
#pragma unroll
      for (int j = 0; j < 4; ++j) {
        const int col = n0 + wn * 64 + j * 16 + l15;
        if (OUT_BF16)
          ((__hip_bfloat16*)Cout)[(size_t)row * N + col] =
              __float2bfloat16(acc[i][j][r]);
        else
          ((float*)Cout)[(size_t)row * N + col] = acc[i][j][r];
      }
    }
}

// ------- RoPE + scramble-scatter: qkv[t][c] -> qb[t'][h*128+d], kb, vb -------
__global__ void rope_scatter(const __hip_bfloat16* __restrict__ qkv,
                             const float* __restrict__ fc,
                             __hip_bfloat16* __restrict__ qb,
                             __hip_bfloat16* __restrict__ kb,
                             __hip_bfloat16* __restrict__ vb) {
  const int p = blockIdx.x * blockDim.x + threadIdx.x;  // 0..1535
  const int t = blockIdx.y;
  const int c = p * 2;
  const int kv = c / 768;
  const int rem = c - kv * 768;
  const int slot = rem >> 7;
  const int d = rem & 127;
  const ushort2 xy = *(const ushort2*)&qkv[(size_t)t * QKVO + c];
  const float x0 = __bfloat162float(*(const __hip_bfloat16*)&xy.x);
  const float x1 = __bfloat162float(*(const __hip_bfloat16*)&xy.y);
  union { ushort2 uu; __hip_bfloat16 b[2]; } o;
  if (slot < 4) {
    const unsigned u = ((unsigned)kv << 14) | ((unsigned)slot << 12) | (unsigned)t;
    const int tp = u >> 4, h = u & 15;
    const float2 cs = *(const float2*)&fc[(size_t)tp * 128 + (d >> 1) * 2];
    o.b[0] = __float2bfloat16(x0 * cs.x - x1 * cs.y);
    o.b[1] = __float2bfloat16(x1 * cs.x + x0 * cs.y);
    *(ushort2*)&qb[(size_t)tp * Cc + h * HD + d] = o.uu;
  } else {
    const unsigned u2 = ((unsigned)kv << 12) | (unsigned)t;
    const int tp = u2 >> 2, hk = u2 & 3;
    if (slot == 4) {
      const float2 cs = *(const float2*)&fc[(size_t)tp * 128 + (d >> 1) * 2];
      o.b[0] = __float2bfloat16(x0 * cs.x - x1 * cs.y);
      o.b[1] = __float2bfloat16(x1 * cs.x + x0 * cs.y);
      *(ushort2*)&kb[(size_t)tp * 512 + hk * HD + d] = o.uu;
    } else {
      o.uu = xy;
      *(ushort2*)&vb[(size_t)tp * 512 + hk * HD + d] = o.uu;
    }
  }
}

// --- banded GQA flash attention (QBLK=128, KVBLK=64, 8 waves) ---------------
// LDS 64KB (kt dbuf 32K + vt single 16K + pl 16K) -> 2 blocks/CU resident.
// Per tile: bar0 -> stage V(t) + prefetch K(t+1) -> QK^T -> softmax -> bar1
// (V ready) -> PV. K prefetch overlaps QK^T+softmax; V stage overlaps QK^T.
// Defer-max (THR=8); per-lane l-sum partials reduced once at the end.
__global__ __launch_bounds__(512) void attn_band(
    const __hip_bfloat16* __restrict__ qb, const __hip_bfloat16* __restrict__ kb,
    const __hip_bfloat16* __restrict__ vbt, __hip_bfloat16* __restrict__ yb) {
  __shared__ __hip_bfloat16 kt[2][64 * 128];   // [j][d], swizzled
  __shared__ __hip_bfloat16 vt[128 * 64];      // [d][j], swizzled, single buf
  __shared__ __hip_bfloat16 pl[8][16 * 64];    // per-wave P round-trip, swizzled
  const int tid = threadIdx.x, lane = tid & 63, wid = tid >> 6;
  const int l15 = lane & 15, lhi = lane >> 4;
  const int q0 = blockIdx.x * 128, h = blockIdx.y;
  const int kvh = h >> 2;
  const int qrow = q0 + wid * 16 + l15;
  short8 aq[4];
#pragma unroll
  for (int kc = 0; kc < 4; ++kc)
    aq[kc] = *(const short8*)&qb[(size_t)qrow * Cc + h * HD + kc * 32 + lhi * 8];
  f32x4 o[8] = {};
  float mrow[4] = {-1e30f, -1e30f, -1e30f, -1e30f};
  float lsum[4] = {0.f, 0.f, 0.f, 0.f};  // per-lane partial, reduced at end
  const int js = (q0 - W1 > 0 ? q0 - W1 : 0) & ~63;
  const int jeu = q0 + 128 + W1;
  const int je = jeu < Tt ? jeu : Tt;
  const int nt = (je - js + 63) >> 6;
  const float scale = 0.08838834764831845f;  // 1/sqrt(128)
  char* ktb = (char*)kt;
  char* vtc = (char*)vt;
  char* plc = (char*)&pl[wid][0];
  const size_t vbase = (size_t)kvh * 524288;

  auto stageK = [&](int j0, int buf) {
    char* kd = ktb + buf * 16384;
#pragma unroll
    for (int cc = 0; cc < 2; ++cc) {
      const int sb = (cc * 8 + wid) << 10;
      const int S = sb + lane * 16;
      const int row = S >> 8;
      const int colb = (S & 255) ^ ((row & 7) << 4);
      int jc = j0 + row;
      jc = jc < Tt - 1 ? jc : Tt - 1;
      GLDS16(kb + (size_t)jc * 512 + kvh * HD + (colb >> 1), kd + sb);
    }
  };
  auto stageV = [&](int j0) {
#pragma unroll
    for (int cc = 0; cc < 2; ++cc) {
      const int sb = (cc * 8 + wid) << 10;
      const int S = sb + lane * 16;
      const int row = S >> 7;
      const int colb = (S & 127) ^ ((row & 7) << 4);
      GLDS16(vbt + vbase + (size_t)row * Tt + j0 + (colb >> 1), vtc + sb);
    }
  };

  stageK(js, 0);
  int cur = 0;
  for (int t = 0; t < nt; ++t) {
    const int j0 = js + t * 64;
    __syncthreads();  // bar0: kt[cur] staged; vt free (all PV(t-1) done)
    stageV(j0);
    if (t + 1 < nt) stageK(j0 + 64, cur ^ 1);
    char* ktc = ktb + cur * 16384;
    // ---- QK^T ----
    f32x4 s[4] = {};
    __builtin_amdgcn_s_setprio(1);
#pragma unroll
    for (int jt = 0; jt < 4; ++jt) {
      const int row = jt * 16 + l15;
      const int sw = (row & 7) << 4;
#pragma unroll
      for (int kc = 0; kc < 4; ++kc) {
        const short8 bk =
            *(const short8*)(ktc + row * 256 + ((kc * 64 + lhi * 16) ^ sw));
        s[jt] = __builtin_amdgcn_mfma_f32_16x16x32_bf16(aq[kc], bk, s[jt], 0, 0, 0);
      }
    }
    __builtin_amdgcn_s_setprio(0);
    // ---- mask + online softmax (defer-max THR=8, deferred l-reduce) ----
    float val[4][4], pm[4];
#pragma unroll
    for (int jt = 0; jt < 4; ++jt)
#pragma unroll
      for (int r = 0; r < 4; ++r) {
        const int j = j0 + jt * 16 + l15;
        const int i = q0 + wid * 16 + lhi * 4 + r;
        const int diff = i > j ? i - j : j - i;
        const bool ok = (j < Tt) && (diff <= W1);
        val[jt][r] = ok ? s[jt][r] * scale : -1e30f;
      }
#pragma unroll
    for (int r = 0; r < 4; ++r) {
      float v = fmaxf(fmaxf(val[0][r], val[1][r]), fmaxf(val[2][r], val[3][r]));
      v = fmaxf(v, __shfl_xor(v, 1));
      v = fmaxf(v, __shfl_xor(v, 2));
      v = fmaxf(v, __shfl_xor(v, 4));
      v = fmaxf(v, __shfl_xor(v, 8));
      pm[r] = v;
    }
    float need = 0.f;
#pragma unroll
    for (int r = 0; r < 4; ++r) need = fmaxf(need, pm[r] - mrow[r]);
    if (!__all(need <= 8.0f)) {
#pragma unroll
      for (int r = 0; r < 4; ++r) {
        const float mn = fmaxf(mrow[r], pm[r]);
        const float esc = __expf(mrow[r] - mn);
        mrow[r] = mn;
        lsum[r] *= esc;
#pragma unroll
        for (int dt = 0; dt < 8; ++dt) o[dt][r] *= esc;
      }
    }
#pragma unroll
    for (int jt = 0; jt < 4; ++jt)
#pragma unroll
      for (int r = 0; r < 4; ++r) {
        const float p = __expf(val[jt][r] - mrow[r]);
        lsum[r] += p;
        const int row = lhi * 4 + r;
        const int b = row * 128 + (((jt * 16 + l15) * 2) ^ ((row & 7) << 4));
        *(__hip_bfloat16*)(plc + b) = __float2bfloat16(p);
      }
    __syncthreads();  // bar1: vt fully staged by all waves; pl (same-wave) done
    // ---- PV ----
    const int psw = (l15 & 7) << 4;
    const short8 pa0 = *(const short8*)(plc + l15 * 128 + ((lhi * 16) ^ psw));
    const short8 pa1 = *(const short8*)(plc + l15 * 128 + ((64 + lhi * 16) ^ psw));
    __builtin_amdgcn_s_setprio(1);
#pragma unroll
    for (int dt = 0; dt < 8; ++dt) {
      const int d = dt * 16 + l15;
      const int vsw = (d & 7) << 4;
      const short8 bv0 = *(const short8*)(vtc + d * 128 + ((lhi * 16) ^ vsw));
      const short8 bv1 = *(const short8*)(vtc + d * 128 + ((64 + lhi * 16) ^ vsw));
      o[dt] = __builtin_amdgcn_mfma_f32_16x16x32_bf16(pa0, bv0, o[dt], 0, 0, 0);
      o[dt] = __builtin_amdgcn_mfma_f32_16x16x32_bf16(pa1, bv1, o[dt], 0, 0, 0);
    }
    __builtin_amdgcn_s_setprio(0);
    cur ^= 1;
  }
  float lrow[4];
#pragma unroll
  for (int r = 0; r < 4; ++r) {
    float v = lsum[r];
    v += __shfl_xor(v, 1);
    v += __shfl_xor(v, 2);
    v += __shfl_xor(v, 4);
    v += __shfl_xor(v, 8);
    lrow[r] = v;
  }
#pragma unroll
  for (int dt = 0; dt < 8; ++dt)
#pragma unroll
    for (int r = 0; r < 4; ++r) {
      const int i = q0 + wid * 16 + lhi * 4 + r;
      yb[(size_t)i * Cc + h * HD + dt * 16 + l15] =
          __float2bfloat16(o[dt][r] / lrow[r]);
    }
}

extern "C" void kernel_launch(void* const* d_in, const int* in_sizes, int n_in,
                              void* d_out, int out_size, void* d_ws,
                              size_t ws_size, hipStream_t stream) {
  const float* x = (const float*)d_in[0];
  const float* fc = (const float*)d_in[1];
  const float* Wa = (const float*)d_in[2];
  const float* Wp = (const float*)d_in[3];
  float* out = (float*)d_out;
  char* ws = (char*)d_ws;
  // workspace layout (60 MB total, overlapped lifetimes):
  //  phase1: xb 0..16 | Wat 16..28 | Wpt 28..36 | qkv 36..60
  //  phase2 (rope):   qb 0..16, kb 16..20, vb 20..24   (over xb/Wat, dead)
  //  phase2b (vtrans): vbt 24..28 (over Wat tail, dead; vb still live)
  //  phase3 (attn):   reads qb/kb/vbt, writes yb 36..52 (over qkv, dead)
  //  phase4 (gemm2):  reads yb + Wpt, writes d_out
  __hip_bfloat16* xb  = (__hip_bfloat16*)(ws);
  __hip_bfloat16* Wat = (__hip_bfloat16*)(ws + (16u << 20));
  __hip_bfloat16* Wpt = (__hip_bfloat16*)(ws + (28u << 20));
  __hip_bfloat16* qkv = (__hip_bfloat16*)(ws + (36u << 20));
  __hip_bfloat16* qb  = (__hip_bfloat16*)(ws);
  __hip_bfloat16* kb  = (__hip_bfloat16*)(ws + (16u << 20));
  __hip_bfloat16* vb  = (__hip_bfloat16*)(ws + (20u << 20));
  __hip_bfloat16* vbt = (__hip_bfloat16*)(ws + (24u << 20));
  __hip_bfloat16* yb  = qkv;

  cvt4<<<dim3(Tt * Cc / 1024), 256, 0, stream>>>(x, xb, Tt * Cc);
  tconv<<<dim3(Cc / 32, QKVO / 32), dim3(32, 8), 0, stream>>>(Wa, Wat, Cc, QKVO);
  tconv<<<dim3(Cc / 32, Cc / 32), dim3(32, 8), 0, stream>>>(Wp, Wpt, Cc, Cc);
  gemm_bt<true><<<dim3(QKVO / 128, Tt / 128), 256, 0, stream>>>(
      xb, Wat, qkv, Tt, QKVO, Cc);
  rope_scatter<<<dim3(6, Tt), 256, 0, stream>>>(qkv, fc, qb, kb, vb);
  vtrans<<<dim3(Tt / 32, HD / 32, 4), dim3(32, 8), 0, stream>>>(vb, vbt);
  attn_band<<<dim3(Tt / 128, NH), 512, 0, stream>>>(qb, kb, vbt, yb);
  gemm_bt<false><<<dim3(Cc / 128, Tt / 128), 256, 0, stream>>>(
      yb, Wpt, out, Tt, Cc, Cc);
}